// Round 1
// baseline (855.642 us; speedup 1.0000x reference)
//
#include <hip/hip_runtime.h>
#include <math.h>

#define DIM    1024
#define BATCH  2
#define SEQ    2048
#define NHEAD  16
#define HDIM   64
#define MROWS  (BATCH*SEQ)   // 4096

// ---------------------------------------------------------------------------
// GEMM (NT): C[M,N] = epilogue( A[M,K] @ B[N,K]^T + bias[N] )
//   mode 0: plain          mode 1: (acc+bias)*scale        (Q projection)
//   mode 2: exact GELU     mode 3: acc+bias+r1+r2          (final residual)
// Tile 64x64, K-step 16, 256 threads, 4x4 microtile per thread.
// LDS tiles stored transposed [k][m] with stride 68 (16B-aligned, padded)
// so fragment reads are ds_read_b128.
// ---------------------------------------------------------------------------
__global__ __launch_bounds__(256)
void gemm_nt(const float* __restrict__ A, const float* __restrict__ B,
             const float* __restrict__ bias, float* __restrict__ C,
             int M, int N, int K, int mode, float scale,
             const float* __restrict__ r1, const float* __restrict__ r2)
{
    __shared__ float As[16 * 68];
    __shared__ float Bs[16 * 68];

    const int tid  = threadIdx.x;
    const int m0   = blockIdx.y * 64;
    const int n0   = blockIdx.x * 64;
    const int lrow = tid >> 2;          // 0..63  (row inside tile, for loads)
    const int lk4  = (tid & 3) << 2;    // 0,4,8,12 (k offset, float4)
    const int tm   = tid >> 4;          // 0..15
    const int tn   = tid & 15;          // 0..15

    float acc[4][4] = {};

    const float* Ap = A + (size_t)(m0 + lrow) * K + lk4;
    const float* Bp = B + (size_t)(n0 + lrow) * K + lk4;

    for (int k0 = 0; k0 < K; k0 += 16) {
        float4 av = *(const float4*)(Ap + k0);
        float4 bv = *(const float4*)(Bp + k0);
        const float* avf = (const float*)&av;
        const float* bvf = (const float*)&bv;
        #pragma unroll
        for (int j = 0; j < 4; j++) {
            As[(lk4 + j) * 68 + lrow] = avf[j];
            Bs[(lk4 + j) * 68 + lrow] = bvf[j];
        }
        __syncthreads();
        #pragma unroll
        for (int kk = 0; kk < 16; kk++) {
            float4 a4 = *(const float4*)&As[kk * 68 + tm * 4];
            float4 b4 = *(const float4*)&Bs[kk * 68 + tn * 4];
            const float* a = (const float*)&a4;
            const float* b = (const float*)&b4;
            #pragma unroll
            for (int i = 0; i < 4; i++)
                #pragma unroll
                for (int j = 0; j < 4; j++)
                    acc[i][j] += a[i] * b[j];
        }
        __syncthreads();
    }

    #pragma unroll
    for (int i = 0; i < 4; i++) {
        const int m = m0 + tm * 4 + i;
        float4 o;
        float* ov = (float*)&o;
        #pragma unroll
        for (int j = 0; j < 4; j++) {
            const int n = n0 + tn * 4 + j;
            float v = acc[i][j] + bias[n];
            if (mode == 1) {
                v *= scale;
            } else if (mode == 2) {
                v = 0.5f * v * (1.0f + erff(v * 0.70710678118654752f));
            } else if (mode == 3) {
                const size_t idx = (size_t)m * N + n;
                v += r1[idx] + r2[idx];
            }
            ov[j] = v;
        }
        *(float4*)(C + (size_t)m * N + n0 + tn * 4) = o;
    }
}

// ---------------------------------------------------------------------------
// KtV[bh][d][e] = sum_s K[b,s,h*64+d] * V[b,s,h*64+e]
// One block per (b,h) = 32 blocks; loops over S in chunks of 128 staged in LDS.
// Thread t: d = t&63, e-range = ((t>>6)*16 .. +15), 16 fp32 accumulators.
// ---------------------------------------------------------------------------
__global__ __launch_bounds__(256)
void ktv_kernel(const float* __restrict__ Kb, const float* __restrict__ Vb,
                float* __restrict__ KtV)
{
    __shared__ float Ks[128 * 68];
    __shared__ float Vs[128 * 68];

    const int tid = threadIdx.x;
    const int bh  = blockIdx.x;          // 0..31
    const int b   = bh >> 4;
    const int h   = bh & 15;
    const int d   = tid & 63;
    const int e0  = (tid >> 6) << 4;     // 0,16,32,48

    float acc[16] = {};
    const size_t base = (size_t)b * SEQ * DIM + (size_t)h * HDIM;

    for (int s0 = 0; s0 < SEQ; s0 += 128) {
        __syncthreads();
        #pragma unroll
        for (int i = 0; i < 8; i++) {
            const int idx = tid + 256 * i;       // 0..2047
            const int r   = idx >> 4;            // 0..127
            const int c4  = (idx & 15) << 2;     // 0..60
            const size_t g = base + (size_t)(s0 + r) * DIM + c4;
            *(float4*)&Ks[r * 68 + c4] = *(const float4*)(Kb + g);
            *(float4*)&Vs[r * 68 + c4] = *(const float4*)(Vb + g);
        }
        __syncthreads();
        for (int r = 0; r < 128; r++) {
            const float kd = Ks[r * 68 + d];
            float4 v0 = *(const float4*)&Vs[r * 68 + e0];
            float4 v1 = *(const float4*)&Vs[r * 68 + e0 + 4];
            float4 v2 = *(const float4*)&Vs[r * 68 + e0 + 8];
            float4 v3 = *(const float4*)&Vs[r * 68 + e0 + 12];
            const float* vv0 = (const float*)&v0;
            const float* vv1 = (const float*)&v1;
            const float* vv2 = (const float*)&v2;
            const float* vv3 = (const float*)&v3;
            #pragma unroll
            for (int j = 0; j < 4; j++) {
                acc[j]      += kd * vv0[j];
                acc[4 + j]  += kd * vv1[j];
                acc[8 + j]  += kd * vv2[j];
                acc[12 + j] += kd * vv3[j];
            }
        }
    }

    float* dst = KtV + (size_t)bh * (HDIM * HDIM) + (size_t)d * HDIM + e0;
    #pragma unroll
    for (int j = 0; j < 16; j += 4) {
        float4 o = { acc[j], acc[j + 1], acc[j + 2], acc[j + 3] };
        *(float4*)(dst + j) = o;
    }
}

// ---------------------------------------------------------------------------
// Out[row, h*64+e] = sum_d Q[row, h*64+d] * KtV[bh][d][e]
// One block per row (4096 blocks). Q row staged in LDS; KtV streamed from L2.
// Thread t computes 4 consecutive outputs c = 4t..4t+3 (single head).
// ---------------------------------------------------------------------------
__global__ __launch_bounds__(256)
void qktv_kernel(const float* __restrict__ Q, const float* __restrict__ KtV,
                 float* __restrict__ Out)
{
    __shared__ float Qs[DIM];
    const int row = blockIdx.x;          // 0..4095
    const int tid = threadIdx.x;
    const int b   = row >> 11;           // row / 2048

    *(float4*)&Qs[tid * 4] = *(const float4*)(Q + (size_t)row * DIM + tid * 4);
    __syncthreads();

    const int c0 = tid * 4;
    const int h  = c0 >> 6;
    const int e0 = c0 & 63;
    const float* kt = KtV + (size_t)(b * NHEAD + h) * (HDIM * HDIM) + e0;
    const float* qh = &Qs[h * HDIM];

    float4 acc = {0.f, 0.f, 0.f, 0.f};
    #pragma unroll 8
    for (int dd = 0; dd < HDIM; dd++) {
        const float qv = qh[dd];
        float4 kv = *(const float4*)(kt + (size_t)dd * HDIM);
        acc.x += qv * kv.x;
        acc.y += qv * kv.y;
        acc.z += qv * kv.z;
        acc.w += qv * kv.w;
    }
    *(float4*)(Out + (size_t)row * DIM + c0) = acc;
}

// ---------------------------------------------------------------------------
extern "C" void kernel_launch(void* const* d_in, const int* in_sizes, int n_in,
                              void* d_out, int out_size, void* d_ws, size_t ws_size,
                              hipStream_t stream)
{
    const float* x  = (const float*)d_in[0];
    const float* Wq = (const float*)d_in[1];
    const float* bq = (const float*)d_in[2];
    const float* Wk = (const float*)d_in[3];
    const float* bk = (const float*)d_in[4];
    const float* Wv = (const float*)d_in[5];
    const float* bv = (const float*)d_in[6];
    const float* W1 = (const float*)d_in[7];
    const float* b1 = (const float*)d_in[8];
    const float* W2 = (const float*)d_in[9];
    const float* b2 = (const float*)d_in[10];
    float* out = (float*)d_out;

    char* ws = (char*)d_ws;
    const size_t MB16 = 16u * 1024u * 1024u;
    float* q    = (float*)(ws);                 // 16 MB
    float* kbuf = (float*)(ws + MB16);          // 16 MB
    float* vbuf = (float*)(ws + 2 * MB16);      // 16 MB
    float* ktv  = (float*)(ws + 3 * MB16);      // 512 KB
    float* attn = kbuf;                         // reuse after ktv done
    float* h1   = vbuf;                         // reuse after ktv done

    const dim3 grid(DIM / 64, MROWS / 64);      // (16, 64)
    const dim3 blk(256);
    const float scale = 0.125f;                 // HEAD_DIM^-0.5

    // Projections (Q fused with *scale)
    gemm_nt<<<grid, blk, 0, stream>>>(x, Wq, bq, q,    MROWS, DIM, DIM, 1, scale,   nullptr, nullptr);
    gemm_nt<<<grid, blk, 0, stream>>>(x, Wk, bk, kbuf, MROWS, DIM, DIM, 0, 1.0f,    nullptr, nullptr);
    gemm_nt<<<grid, blk, 0, stream>>>(x, Wv, bv, vbuf, MROWS, DIM, DIM, 0, 1.0f,    nullptr, nullptr);

    // Attention via associativity: out = Q @ (K^T V) per head
    ktv_kernel<<<dim3(BATCH * NHEAD), blk, 0, stream>>>(kbuf, vbuf, ktv);
    qktv_kernel<<<dim3(MROWS), blk, 0, stream>>>(q, ktv, attn);

    // MLP: h1 = gelu(attn @ W1^T + b1);  out = x + attn + (h1 @ W2^T + b2)
    gemm_nt<<<grid, blk, 0, stream>>>(attn, W1, b1, h1, MROWS, DIM, DIM, 2, 1.0f, nullptr, nullptr);
    gemm_nt<<<grid, blk, 0, stream>>>(h1,   W2, b2, out, MROWS, DIM, DIM, 3, 1.0f, x, attn);
}

// Round 2
// 365.233 us; speedup vs baseline: 2.3427x; 2.3427x over previous
//
#include <hip/hip_runtime.h>
#include <math.h>

#define DIM    1024
#define BATCH  2
#define SEQ    2048
#define NHEAD  16
#define HDIM   64
#define MROWS  (BATCH*SEQ)   // 4096

typedef unsigned short u16;
typedef __attribute__((ext_vector_type(8))) short  s16x8;   // 8 bf16 = 4 VGPRs
typedef __attribute__((ext_vector_type(4))) float  f32x4;

typedef __attribute__((address_space(3))) unsigned int       lds_u32_t;
typedef const __attribute__((address_space(1))) unsigned int glb_u32_t;

__device__ __forceinline__ float bf2f(u16 h) {
    unsigned u = ((unsigned)h) << 16; float f; __builtin_memcpy(&f, &u, 4); return f;
}
__device__ __forceinline__ u16 f2bf(float f) {
    unsigned u; __builtin_memcpy(&u, &f, 4);
    u += 0x7FFFu + ((u >> 16) & 1u);           // round-to-nearest-even
    return (u16)(u >> 16);
}

// ---------------------------------------------------------------------------
// fp32 -> bf16 pack, 4 elems/thread
// ---------------------------------------------------------------------------
__global__ __launch_bounds__(256)
void f2bf_kernel(const float* __restrict__ src, u16* __restrict__ dst, int n4)
{
    int i = blockIdx.x * 256 + threadIdx.x;
    if (i >= n4) return;
    float4 v = ((const float4*)src)[i];
    ushort4 o = { f2bf(v.x), f2bf(v.y), f2bf(v.z), f2bf(v.w) };
    ((ushort4*)dst)[i] = o;
}

// ---------------------------------------------------------------------------
// Shared MFMA-GEMM core: C[128x128] tile of A[M,K=1024] @ B[N,K=1024]^T (bf16)
// 256 threads = 4 waves (2x2), each wave 64x64 via 4x4 of 16x16x32 MFMAs.
// LDS tiles 128x32 bf16 row-major (64 B rows), staged with global_load_lds x16B.
// ---------------------------------------------------------------------------
__device__ __forceinline__ void stage_tile(const u16* __restrict__ gbase, int k0,
                                           u16* lds, int tid)
{
    #pragma unroll
    for (int p = 0; p < 2; ++p) {
        int e   = p * 256 + tid;           // 0..511, 16B chunk id
        int row = e >> 2;                  // 0..127
        int cg  = e & 3;                   // colgroup of 8 bf16
        const u16* src = gbase + (size_t)row * DIM + k0 + cg * 8;
        __builtin_amdgcn_global_load_lds((glb_u32_t*)src, (lds_u32_t*)(lds + e * 8), 16, 0, 0);
    }
}

__device__ __forceinline__ void gemm_core(const u16* __restrict__ Ab,
                                          const u16* __restrict__ Bb,
                                          u16* As, u16* Bs, int tid,
                                          int wm, int wn, int lr, int kq,
                                          f32x4 acc[4][4])
{
    for (int k0 = 0; k0 < DIM; k0 += 32) {
        stage_tile(Ab, k0, As, tid);
        stage_tile(Bb, k0, Bs, tid);
        __syncthreads();
        s16x8 af[4], bfr[4];
        #pragma unroll
        for (int i = 0; i < 4; ++i)
            af[i]  = *(const s16x8*)(As + (wm + i * 16 + lr) * 32 + kq * 8);
        #pragma unroll
        for (int j = 0; j < 4; ++j)
            bfr[j] = *(const s16x8*)(Bs + (wn + j * 16 + lr) * 32 + kq * 8);
        #pragma unroll
        for (int i = 0; i < 4; ++i)
            #pragma unroll
            for (int j = 0; j < 4; ++j)
                acc[i][j] = __builtin_amdgcn_mfma_f32_16x16x32_bf16(af[i], bfr[j], acc[i][j], 0, 0, 0);
        __syncthreads();
    }
}

// ---------------------------------------------------------------------------
// Fused QKV projection: grid (24, 32). blockIdx.x>>3 selects {Q,K,V}.
// Output bf16; Q scaled by HEAD_DIM^-0.5.
// ---------------------------------------------------------------------------
__global__ __launch_bounds__(256)
void qkv_gemm(const u16* __restrict__ xb,
              const u16* __restrict__ Wq, const u16* __restrict__ Wk, const u16* __restrict__ Wv,
              const float* __restrict__ bq, const float* __restrict__ bk, const float* __restrict__ bv,
              u16* __restrict__ qo, u16* __restrict__ ko, u16* __restrict__ vo)
{
    __shared__ u16 As[128 * 32];
    __shared__ u16 Bs[128 * 32];
    const int tid = threadIdx.x;
    const int sel = blockIdx.x >> 3;
    const int n0  = (blockIdx.x & 7) * 128;
    const int m0  = blockIdx.y * 128;
    const u16*   B    = (sel == 0) ? Wq : (sel == 1) ? Wk : Wv;
    const float* bias = (sel == 0) ? bq : (sel == 1) ? bk : bv;
    u16*         C    = (sel == 0) ? qo : (sel == 1) ? ko : vo;
    const float scale = (sel == 0) ? 0.125f : 1.0f;

    const int w = tid >> 6, l = tid & 63;
    const int wm = (w >> 1) * 64, wn = (w & 1) * 64;
    const int lr = l & 15, kq = l >> 4;

    f32x4 acc[4][4];
    #pragma unroll
    for (int i = 0; i < 4; ++i)
        #pragma unroll
        for (int j = 0; j < 4; ++j) acc[i][j] = (f32x4){0.f, 0.f, 0.f, 0.f};

    gemm_core(xb + (size_t)m0 * DIM, B + (size_t)n0 * DIM, As, Bs, tid, wm, wn, lr, kq, acc);

    const int er = l >> 4, ec = l & 15;
    #pragma unroll
    for (int j = 0; j < 4; ++j) {
        const int n = n0 + wn + j * 16 + ec;
        const float bv2 = bias[n];
        #pragma unroll
        for (int i = 0; i < 4; ++i)
            #pragma unroll
            for (int r = 0; r < 4; ++r) {
                const int m = m0 + wm + i * 16 + er * 4 + r;
                C[(size_t)m * DIM + n] = f2bf((acc[i][j][r] + bv2) * scale);
            }
    }
}

// ---------------------------------------------------------------------------
// MLP GEMMs. mode 1: gelu -> bf16 out.  mode 2: +bias +x +attn -> fp32 out.
// grid (8, 32).
// ---------------------------------------------------------------------------
__global__ __launch_bounds__(256)
void gemm_bf16(const u16* __restrict__ A, const u16* __restrict__ B,
               const float* __restrict__ bias,
               u16* __restrict__ Cb, float* __restrict__ Cf,
               const float* __restrict__ rx, const u16* __restrict__ rattn,
               int mode)
{
    __shared__ u16 As[128 * 32];
    __shared__ u16 Bs[128 * 32];
    const int tid = threadIdx.x;
    const int n0 = blockIdx.x * 128, m0 = blockIdx.y * 128;
    const int w = tid >> 6, l = tid & 63;
    const int wm = (w >> 1) * 64, wn = (w & 1) * 64;
    const int lr = l & 15, kq = l >> 4;

    f32x4 acc[4][4];
    #pragma unroll
    for (int i = 0; i < 4; ++i)
        #pragma unroll
        for (int j = 0; j < 4; ++j) acc[i][j] = (f32x4){0.f, 0.f, 0.f, 0.f};

    gemm_core(A + (size_t)m0 * DIM, B + (size_t)n0 * DIM, As, Bs, tid, wm, wn, lr, kq, acc);

    const int er = l >> 4, ec = l & 15;
    #pragma unroll
    for (int j = 0; j < 4; ++j) {
        const int n = n0 + wn + j * 16 + ec;
        const float bv2 = bias[n];
        #pragma unroll
        for (int i = 0; i < 4; ++i)
            #pragma unroll
            for (int r = 0; r < 4; ++r) {
                const int m = m0 + wm + i * 16 + er * 4 + r;
                const size_t idx = (size_t)m * DIM + n;
                float v = acc[i][j][r] + bv2;
                if (mode == 1) {
                    v = 0.5f * v * (1.0f + erff(v * 0.70710678118654752f));
                    Cb[idx] = f2bf(v);
                } else {
                    Cf[idx] = v + rx[idx] + bf2f(rattn[idx]);
                }
            }
    }
}

// ---------------------------------------------------------------------------
// KtV[bh][d][e] = sum_s K[b,s,h,d] * V[b,s,h,e]; split-S 16-way, atomicAdd.
// grid 512 = 16 s-chunks x 32 (b,h). fp32 accumulation from bf16 K/V.
// ---------------------------------------------------------------------------
__global__ __launch_bounds__(256)
void ktv_kernel(const u16* __restrict__ Kb, const u16* __restrict__ Vb,
                float* __restrict__ KtV)
{
    __shared__ float Ks[128 * 68];
    __shared__ float Vs[128 * 68];
    const int tid = threadIdx.x;
    const int bh  = blockIdx.x & 31;
    const int sc  = blockIdx.x >> 5;
    const int b = bh >> 4, h = bh & 15;
    const int d = tid & 63;
    const int e0 = (tid >> 6) << 4;
    const size_t base = (size_t)b * SEQ * DIM + (size_t)h * HDIM + (size_t)sc * 128 * DIM;

    #pragma unroll
    for (int i = 0; i < 8; ++i) {
        int gid = i * 256 + tid;            // 0..2047
        int r = gid >> 4, c4 = (gid & 15) << 2;
        size_t g = base + (size_t)r * DIM + c4;
        ushort4 kv = *(const ushort4*)(Kb + g);
        ushort4 vv = *(const ushort4*)(Vb + g);
        *(float4*)&Ks[r * 68 + c4] = make_float4(bf2f(kv.x), bf2f(kv.y), bf2f(kv.z), bf2f(kv.w));
        *(float4*)&Vs[r * 68 + c4] = make_float4(bf2f(vv.x), bf2f(vv.y), bf2f(vv.z), bf2f(vv.w));
    }
    __syncthreads();

    float acc[16] = {};
    for (int r = 0; r < 128; ++r) {
        const float kd = Ks[r * 68 + d];
        const float* vp = &Vs[r * 68 + e0];
        #pragma unroll
        for (int j = 0; j < 16; ++j) acc[j] += kd * vp[j];
    }
    float* dst = KtV + (size_t)bh * (HDIM * HDIM) + (size_t)d * HDIM + e0;
    #pragma unroll
    for (int j = 0; j < 16; ++j) atomicAdd(dst + j, acc[j]);
}

// ---------------------------------------------------------------------------
// attn[row,c] = sum_d Q[row,d_h] * KtV[bh][d][e]; one block per row. bf16 out.
// ---------------------------------------------------------------------------
__global__ __launch_bounds__(256)
void qktv_kernel(const u16* __restrict__ Qb, const float* __restrict__ KtV,
                 u16* __restrict__ Outb)
{
    __shared__ float Qs[DIM];
    const int row = blockIdx.x, tid = threadIdx.x;
    const int b = row >> 11;
    ushort4 qv = *(const ushort4*)(Qb + (size_t)row * DIM + tid * 4);
    Qs[tid * 4 + 0] = bf2f(qv.x); Qs[tid * 4 + 1] = bf2f(qv.y);
    Qs[tid * 4 + 2] = bf2f(qv.z); Qs[tid * 4 + 3] = bf2f(qv.w);
    __syncthreads();

    const int c0 = tid * 4, h = c0 >> 6, e0 = c0 & 63;
    const float* kt = KtV + (size_t)(b * NHEAD + h) * (HDIM * HDIM) + e0;
    const float* qh = &Qs[h * HDIM];

    float4 a = {0.f, 0.f, 0.f, 0.f};
    #pragma unroll 8
    for (int dd = 0; dd < HDIM; ++dd) {
        const float q = qh[dd];
        float4 kvv = *(const float4*)(kt + (size_t)dd * HDIM);
        a.x += q * kvv.x; a.y += q * kvv.y; a.z += q * kvv.z; a.w += q * kvv.w;
    }
    ushort4 o = { f2bf(a.x), f2bf(a.y), f2bf(a.z), f2bf(a.w) };
    *(ushort4*)(Outb + (size_t)row * DIM + c0) = o;
}

// ---------------------------------------------------------------------------
extern "C" void kernel_launch(void* const* d_in, const int* in_sizes, int n_in,
                              void* d_out, int out_size, void* d_ws, size_t ws_size,
                              hipStream_t stream)
{
    const float* x  = (const float*)d_in[0];
    const float* Wq = (const float*)d_in[1];
    const float* bq = (const float*)d_in[2];
    const float* Wk = (const float*)d_in[3];
    const float* bk = (const float*)d_in[4];
    const float* Wv = (const float*)d_in[5];
    const float* bv = (const float*)d_in[6];
    const float* W1 = (const float*)d_in[7];
    const float* b1 = (const float*)d_in[8];
    const float* W2 = (const float*)d_in[9];
    const float* b2 = (const float*)d_in[10];
    float* out = (float*)d_out;

    char* ws = (char*)d_ws;
    const size_t MB = 1u << 20;
    u16* xb   = (u16*)(ws);             //  8 MB  bf16 x
    u16* Wqb  = (u16*)(ws +  8 * MB);   //  2 MB
    u16* Wkb  = (u16*)(ws + 10 * MB);
    u16* Wvb  = (u16*)(ws + 12 * MB);
    u16* W1b  = (u16*)(ws + 14 * MB);
    u16* W2b  = (u16*)(ws + 16 * MB);
    u16* qb   = (u16*)(ws + 18 * MB);   //  8 MB
    u16* kb   = (u16*)(ws + 26 * MB);   //  8 MB
    u16* vb   = (u16*)(ws + 34 * MB);   //  8 MB
    float* ktv = (float*)(ws + 42 * MB); // 512 KB
    u16* attnb = kb;                    // reuse after ktv consumes kb
    u16* h1b   = vb;                    // reuse after ktv consumes vb

    hipMemsetAsync(ktv, 0, BATCH * NHEAD * HDIM * HDIM * sizeof(float), stream);

    // fp32 -> bf16 packs
    f2bf_kernel<<<4096, 256, 0, stream>>>(x,  xb,  MROWS * DIM / 4);
    f2bf_kernel<<<1024, 256, 0, stream>>>(Wq, Wqb, DIM * DIM / 4);
    f2bf_kernel<<<1024, 256, 0, stream>>>(Wk, Wkb, DIM * DIM / 4);
    f2bf_kernel<<<1024, 256, 0, stream>>>(Wv, Wvb, DIM * DIM / 4);
    f2bf_kernel<<<1024, 256, 0, stream>>>(W1, W1b, DIM * DIM / 4);
    f2bf_kernel<<<1024, 256, 0, stream>>>(W2, W2b, DIM * DIM / 4);

    // fused QKV projection (768 blocks = 3/CU)
    qkv_gemm<<<dim3(24, 32), 256, 0, stream>>>(xb, Wqb, Wkb, Wvb, bq, bk, bv, qb, kb, vb);

    // attention via associativity
    ktv_kernel<<<512, 256, 0, stream>>>(kb, vb, ktv);
    qktv_kernel<<<MROWS, 256, 0, stream>>>(qb, ktv, attnb);

    // MLP
    gemm_bf16<<<dim3(8, 32), 256, 0, stream>>>(attnb, W1b, b1, h1b, nullptr, nullptr, nullptr, 1);
    gemm_bf16<<<dim3(8, 32), 256, 0, stream>>>(h1b, W2b, b2, nullptr, out, x, attnb, 2);
}

// Round 3
// 209.198 us; speedup vs baseline: 4.0901x; 1.7459x over previous
//
#include <hip/hip_runtime.h>
#include <math.h>

#define DIM    1024
#define BATCH  2
#define SEQ    2048
#define NHEAD  16
#define HDIM   64
#define MROWS  (BATCH*SEQ)   // 4096
#define NSPLIT 8             // ktv S-splits (2048/8 = 256 s per block)

typedef unsigned short u16;
typedef __attribute__((ext_vector_type(8))) short  s16x8;   // 8 bf16 = 4 VGPRs
typedef __attribute__((ext_vector_type(4))) float  f32x4;

typedef __attribute__((address_space(3))) unsigned int       lds_u32_t;
typedef const __attribute__((address_space(1))) unsigned int glb_u32_t;

__device__ __forceinline__ float bf2f(u16 h) {
    unsigned u = ((unsigned)h) << 16; float f; __builtin_memcpy(&f, &u, 4); return f;
}
__device__ __forceinline__ u16 f2bf(float f) {
    unsigned u; __builtin_memcpy(&u, &f, 4);
    u += 0x7FFFu + ((u >> 16) & 1u);           // round-to-nearest-even
    return (u16)(u >> 16);
}

// ---------------------------------------------------------------------------
// Fused fp32->bf16 pack for x + 5 weights. One launch.
// grid: 4096 (x) + 5*1024 (weights). 1 float4 per thread.
// ---------------------------------------------------------------------------
__global__ __launch_bounds__(256)
void pack_all(const float* __restrict__ x,
              const float* __restrict__ Wq, const float* __restrict__ Wk,
              const float* __restrict__ Wv, const float* __restrict__ W1,
              const float* __restrict__ W2,
              u16* __restrict__ xb, u16* __restrict__ Wqb, u16* __restrict__ Wkb,
              u16* __restrict__ Wvb, u16* __restrict__ W1b, u16* __restrict__ W2b)
{
    const int bid = blockIdx.x;
    const float* src; u16* dst; int i;
    if (bid < 4096) { src = x; dst = xb; i = bid * 256 + threadIdx.x; }
    else {
        const int w = (bid - 4096) >> 10;
        const int lb = (bid - 4096) & 1023;
        src = (w == 0) ? Wq : (w == 1) ? Wk : (w == 2) ? Wv : (w == 3) ? W1 : W2;
        dst = (w == 0) ? Wqb : (w == 1) ? Wkb : (w == 2) ? Wvb : (w == 3) ? W1b : W2b;
        i = lb * 256 + threadIdx.x;
    }
    float4 v = ((const float4*)src)[i];
    ushort4 o = { f2bf(v.x), f2bf(v.y), f2bf(v.z), f2bf(v.w) };
    ((ushort4*)dst)[i] = o;
}

// ---------------------------------------------------------------------------
// MFMA GEMM core, 512 threads = 8 waves (4 m-waves x 2 n-waves), tile 128x128.
// Wave tile 32x64 = 2x4 MFMAs of 16x16x32_bf16. LDS 128x32 bf16 per operand,
// staged via global_load_lds width=16 (1 chunk/thread/operand per k-step).
// ---------------------------------------------------------------------------
__device__ __forceinline__ void gemm_core8(const u16* __restrict__ Ab,
                                           const u16* __restrict__ Bb,
                                           u16* As, u16* Bs, int tid,
                                           f32x4 acc[2][4])
{
    const int w  = tid >> 6, l = tid & 63;
    const int wm = (w >> 1) * 32, wn = (w & 1) * 64;
    const int lr = l & 15, kq = l >> 4;
    const int row = tid >> 2, cg = tid & 3;

    for (int k0 = 0; k0 < DIM; k0 += 32) {
        const u16* srcA = Ab + (size_t)row * DIM + k0 + cg * 8;
        const u16* srcB = Bb + (size_t)row * DIM + k0 + cg * 8;
        __builtin_amdgcn_global_load_lds((glb_u32_t*)srcA, (lds_u32_t*)(As + tid * 8), 16, 0, 0);
        __builtin_amdgcn_global_load_lds((glb_u32_t*)srcB, (lds_u32_t*)(Bs + tid * 8), 16, 0, 0);
        __syncthreads();
        s16x8 af[2], bfr[4];
        #pragma unroll
        for (int i = 0; i < 2; ++i)
            af[i]  = *(const s16x8*)(As + (wm + i * 16 + lr) * 32 + kq * 8);
        #pragma unroll
        for (int j = 0; j < 4; ++j)
            bfr[j] = *(const s16x8*)(Bs + (wn + j * 16 + lr) * 32 + kq * 8);
        #pragma unroll
        for (int i = 0; i < 2; ++i)
            #pragma unroll
            for (int j = 0; j < 4; ++j)
                acc[i][j] = __builtin_amdgcn_mfma_f32_16x16x32_bf16(af[i], bfr[j], acc[i][j], 0, 0, 0);
        __syncthreads();
    }
}

// ---------------------------------------------------------------------------
// Fused QKV projection: grid (24, 32), 512 threads. blockIdx.x>>3 -> {Q,K,V}.
// ---------------------------------------------------------------------------
__global__ __launch_bounds__(512)
void qkv_gemm(const u16* __restrict__ xb,
              const u16* __restrict__ Wq, const u16* __restrict__ Wk, const u16* __restrict__ Wv,
              const float* __restrict__ bq, const float* __restrict__ bk, const float* __restrict__ bv,
              u16* __restrict__ qo, u16* __restrict__ ko, u16* __restrict__ vo)
{
    __shared__ u16 As[128 * 32];
    __shared__ u16 Bs[128 * 32];
    const int tid = threadIdx.x;
    const int sel = blockIdx.x >> 3;
    const int n0  = (blockIdx.x & 7) * 128;
    const int m0  = blockIdx.y * 128;
    const u16*   B    = (sel == 0) ? Wq : (sel == 1) ? Wk : Wv;
    const float* bias = (sel == 0) ? bq : (sel == 1) ? bk : bv;
    u16*         C    = (sel == 0) ? qo : (sel == 1) ? ko : vo;
    const float scale = (sel == 0) ? 0.125f : 1.0f;

    f32x4 acc[2][4];
    #pragma unroll
    for (int i = 0; i < 2; ++i)
        #pragma unroll
        for (int j = 0; j < 4; ++j) acc[i][j] = (f32x4){0.f, 0.f, 0.f, 0.f};

    gemm_core8(xb + (size_t)m0 * DIM, B + (size_t)n0 * DIM, As, Bs, tid, acc);

    const int w = tid >> 6, l = tid & 63;
    const int wm = (w >> 1) * 32, wn = (w & 1) * 64;
    const int er = l >> 4, ec = l & 15;
    #pragma unroll
    for (int j = 0; j < 4; ++j) {
        const int n = n0 + wn + j * 16 + ec;
        const float bb = bias[n];
        #pragma unroll
        for (int i = 0; i < 2; ++i)
            #pragma unroll
            for (int r = 0; r < 4; ++r) {
                const int m = m0 + wm + i * 16 + er * 4 + r;
                C[(size_t)m * DIM + n] = f2bf((acc[i][j][r] + bb) * scale);
            }
    }
}

// ---------------------------------------------------------------------------
// MLP GEMMs, 512 threads, grid (8, 32).
// mode 1: gelu -> bf16.   mode 2: +bias +x +attn -> fp32.
// ---------------------------------------------------------------------------
__global__ __launch_bounds__(512)
void gemm_bf16(const u16* __restrict__ A, const u16* __restrict__ B,
               const float* __restrict__ bias,
               u16* __restrict__ Cb, float* __restrict__ Cf,
               const float* __restrict__ rx, const u16* __restrict__ rattn,
               int mode)
{
    __shared__ u16 As[128 * 32];
    __shared__ u16 Bs[128 * 32];
    const int tid = threadIdx.x;
    const int n0 = blockIdx.x * 128, m0 = blockIdx.y * 128;

    f32x4 acc[2][4];
    #pragma unroll
    for (int i = 0; i < 2; ++i)
        #pragma unroll
        for (int j = 0; j < 4; ++j) acc[i][j] = (f32x4){0.f, 0.f, 0.f, 0.f};

    gemm_core8(A + (size_t)m0 * DIM, B + (size_t)n0 * DIM, As, Bs, tid, acc);

    const int w = tid >> 6, l = tid & 63;
    const int wm = (w >> 1) * 32, wn = (w & 1) * 64;
    const int er = l >> 4, ec = l & 15;
    #pragma unroll
    for (int j = 0; j < 4; ++j) {
        const int n = n0 + wn + j * 16 + ec;
        const float bb = bias[n];
        #pragma unroll
        for (int i = 0; i < 2; ++i)
            #pragma unroll
            for (int r = 0; r < 4; ++r) {
                const int m = m0 + wm + i * 16 + er * 4 + r;
                const size_t idx = (size_t)m * DIM + n;
                float v = acc[i][j][r] + bb;
                if (mode == 1) {
                    v = 0.5f * v * (1.0f + erff(v * 0.70710678118654752f));
                    Cb[idx] = f2bf(v);
                } else {
                    Cf[idx] = v + rx[idx] + bf2f(rattn[idx]);
                }
            }
    }
}

// ---------------------------------------------------------------------------
// ktv via MFMA, no atomics. grid 256 = 32 (b,h) x 8 s-splits, 256 threads.
// part[sp][bh][d][e] (fp32). K,V tiles transposed into LDS [d][s], stride 264.
// ---------------------------------------------------------------------------
__global__ __launch_bounds__(256)
void ktv_mfma(const u16* __restrict__ Kb, const u16* __restrict__ Vb,
              float* __restrict__ part)
{
    __shared__ u16 Kt[64 * 264];
    __shared__ u16 Vt[64 * 264];
    const int tid = threadIdx.x;
    const int bh = blockIdx.x & 31;
    const int sp = blockIdx.x >> 5;
    const int b = bh >> 4, h = bh & 15;
    const size_t base = (size_t)b * SEQ * DIM + (size_t)h * HDIM + (size_t)sp * 256 * DIM;

    // stage transposed: thread t covers s=(t>>4)+16*pass, d-group (t&15)*4
    const int dg = (tid & 15) * 4;
    #pragma unroll
    for (int pass = 0; pass < 16; ++pass) {
        const int s = (tid >> 4) + 16 * pass;
        ushort4 kv = *(const ushort4*)(Kb + base + (size_t)s * DIM + dg);
        ushort4 vv = *(const ushort4*)(Vb + base + (size_t)s * DIM + dg);
        Kt[(dg + 0) * 264 + s] = kv.x; Kt[(dg + 1) * 264 + s] = kv.y;
        Kt[(dg + 2) * 264 + s] = kv.z; Kt[(dg + 3) * 264 + s] = kv.w;
        Vt[(dg + 0) * 264 + s] = vv.x; Vt[(dg + 1) * 264 + s] = vv.y;
        Vt[(dg + 2) * 264 + s] = vv.z; Vt[(dg + 3) * 264 + s] = vv.w;
    }
    __syncthreads();

    // compute: wave w owns d-range [w*16, w*16+16), full e
    const int w = tid >> 6, l = tid & 63;
    const int lr = l & 15, kq = l >> 4;
    f32x4 acc[4];
    #pragma unroll
    for (int j = 0; j < 4; ++j) acc[j] = (f32x4){0.f, 0.f, 0.f, 0.f};

    for (int k0 = 0; k0 < 256; k0 += 32) {
        s16x8 af = *(const s16x8*)(Kt + (w * 16 + lr) * 264 + k0 + kq * 8);
        #pragma unroll
        for (int j = 0; j < 4; ++j) {
            s16x8 bf = *(const s16x8*)(Vt + (j * 16 + lr) * 264 + k0 + kq * 8);
            acc[j] = __builtin_amdgcn_mfma_f32_16x16x32_bf16(af, bf, acc[j], 0, 0, 0);
        }
    }

    float* dst = part + ((size_t)sp * 32 + bh) * (HDIM * HDIM);
    const int er = l >> 4, ec = l & 15;
    #pragma unroll
    for (int j = 0; j < 4; ++j)
        #pragma unroll
        for (int r = 0; r < 4; ++r)
            dst[(w * 16 + er * 4 + r) * HDIM + j * 16 + ec] = acc[j][r];
}

// ---------------------------------------------------------------------------
// attn = Q @ KtV (block-diag per head), fused partial-reduction.
// grid (16 heads, 32 row-tiles of 128), 256 threads. bf16 out.
// ---------------------------------------------------------------------------
__global__ __launch_bounds__(256)
void qktv_kernel(const u16* __restrict__ Qb, const float* __restrict__ part,
                 u16* __restrict__ attnb)
{
    __shared__ float KV[HDIM * HDIM];    // [d][e] 16 KB
    __shared__ u16 Qs[128 * 68];         // [row][d], stride 68 (8B-aligned)
    const int tid = threadIdx.x;
    const int h  = blockIdx.x;
    const int mt = blockIdx.y;
    const int row0 = mt * 128;
    const int b = row0 >> 11;
    const int bh = b * NHEAD + h;

    // reduce 8 partials into KV
    for (int i = tid; i < HDIM * HDIM; i += 256) {
        float s = 0.f;
        #pragma unroll
        for (int sp = 0; sp < NSPLIT; ++sp)
            s += part[((size_t)sp * 32 + bh) * (HDIM * HDIM) + i];
        KV[i] = s;
    }
    // stage Q tile (rows row0..+128, cols h*64..+64)
    const int dg = (tid & 15) * 4;
    #pragma unroll
    for (int pass = 0; pass < 8; ++pass) {
        const int r = (tid >> 4) + 16 * pass;
        ushort4 q = *(const ushort4*)(Qb + (size_t)(row0 + r) * DIM + h * HDIM + dg);
        *(ushort4*)(Qs + r * 68 + dg) = q;
    }
    __syncthreads();

    const int tr = tid >> 3, tc = tid & 7;   // 32 x 8
    const int r0 = tr * 4, c0 = tc * 8;
    float acc[4][8] = {};
    for (int d = 0; d < HDIM; ++d) {
        float4 ka = *(const float4*)&KV[d * HDIM + c0];
        float4 kb2 = *(const float4*)&KV[d * HDIM + c0 + 4];
        const float* k8a = (const float*)&ka;
        const float* k8b = (const float*)&kb2;
        float qv[4];
        #pragma unroll
        for (int i = 0; i < 4; ++i) qv[i] = bf2f(Qs[(r0 + i) * 68 + d]);
        #pragma unroll
        for (int i = 0; i < 4; ++i)
            #pragma unroll
            for (int j = 0; j < 4; ++j) {
                acc[i][j]     += qv[i] * k8a[j];
                acc[i][j + 4] += qv[i] * k8b[j];
            }
    }
    #pragma unroll
    for (int i = 0; i < 4; ++i) {
        u16* dst = attnb + (size_t)(row0 + r0 + i) * DIM + h * HDIM + c0;
        ushort4 o0 = { f2bf(acc[i][0]), f2bf(acc[i][1]), f2bf(acc[i][2]), f2bf(acc[i][3]) };
        ushort4 o1 = { f2bf(acc[i][4]), f2bf(acc[i][5]), f2bf(acc[i][6]), f2bf(acc[i][7]) };
        *(ushort4*)(dst)     = o0;
        *(ushort4*)(dst + 4) = o1;
    }
}

// ---------------------------------------------------------------------------
extern "C" void kernel_launch(void* const* d_in, const int* in_sizes, int n_in,
                              void* d_out, int out_size, void* d_ws, size_t ws_size,
                              hipStream_t stream)
{
    const float* x  = (const float*)d_in[0];
    const float* Wq = (const float*)d_in[1];
    const float* bq = (const float*)d_in[2];
    const float* Wk = (const float*)d_in[3];
    const float* bk = (const float*)d_in[4];
    const float* Wv = (const float*)d_in[5];
    const float* bv = (const float*)d_in[6];
    const float* W1 = (const float*)d_in[7];
    const float* b1 = (const float*)d_in[8];
    const float* W2 = (const float*)d_in[9];
    const float* b2 = (const float*)d_in[10];
    float* out = (float*)d_out;

    char* ws = (char*)d_ws;
    const size_t MB = 1u << 20;
    u16* xb   = (u16*)(ws);              //  8 MB
    u16* Wqb  = (u16*)(ws +  8 * MB);    //  2 MB each
    u16* Wkb  = (u16*)(ws + 10 * MB);
    u16* Wvb  = (u16*)(ws + 12 * MB);
    u16* W1b  = (u16*)(ws + 14 * MB);
    u16* W2b  = (u16*)(ws + 16 * MB);
    u16* qb   = (u16*)(ws + 18 * MB);    //  8 MB
    u16* kb   = (u16*)(ws + 26 * MB);    //  8 MB
    u16* vb   = (u16*)(ws + 34 * MB);    //  8 MB
    float* part = (float*)(ws + 42 * MB);//  4 MB (8 splits x 32 bh x 64 x 64 fp32)
    u16* attnb = kb;                     // reuse after ktv consumes kb
    u16* h1b   = vb;                     // reuse after ktv consumes vb

    // one fused pack launch
    pack_all<<<4096 + 5 * 1024, 256, 0, stream>>>(x, Wq, Wk, Wv, W1, W2,
                                                  xb, Wqb, Wkb, Wvb, W1b, W2b);

    // fused QKV projection (768 blocks x 8 waves)
    qkv_gemm<<<dim3(24, 32), 512, 0, stream>>>(xb, Wqb, Wkb, Wvb, bq, bk, bv, qb, kb, vb);

    // attention via associativity: KtV partials (MFMA) then Q @ KtV w/ fused reduce
    ktv_mfma<<<NSPLIT * 32, 256, 0, stream>>>(kb, vb, part);
    qktv_kernel<<<dim3(NHEAD, MROWS / 128), 256, 0, stream>>>(qb, part, attnb);

    // MLP
    gemm_bf16<<<dim3(8, 32), 512, 0, stream>>>(attnb, W1b, b1, h1b, nullptr, nullptr, nullptr, 1);
    gemm_bf16<<<dim3(8, 32), 512, 0, stream>>>(h1b, W2b, b2, nullptr, out, x, attnb, 2);
}